// Round 6
// baseline (395.288 us; speedup 1.0000x reference)
//
#include <hip/hip_runtime.h>
#include <hip/hip_bf16.h>
#include <stdint.h>
#include <stddef.h>

typedef __bf16 bf16_t;
typedef __bf16 bf16x4 __attribute__((ext_vector_type(4)));
typedef __bf16 bf16x8 __attribute__((ext_vector_type(8)));
typedef float floatx4 __attribute__((ext_vector_type(4)));

#define NN 20000
#define EE 320000
#define DD 512
#define CAP 96
#define NBLK 313                 // ceil(20000/64) row-blocks of 64
#define BETA1 0.6931471805599453f
#define BETA2 0.40546510810816444f

// ---------------------------------------------------------------------------
// Blocked (MFMA-fragment-native) layout for GEMM operands:
//   X2[blk=row/64][kc=k/8][r=row%64][8 bf16]   (16B chunk per (blk,kc,r))
// A wave's fragment load (lane = quad*16+m16) is a single coalesced
// global_load_dwordx4: 4 quads x 256B contiguous runs. No LDS, no barriers.
// Round-6: register ping-pong prefetch (round-5 showed the compiler
// serializes {load; vmcnt(0); mfma} at VGPR=56 — named dual fragment sets
// force depth-1 overlap, vmcnt(6) before each MFMA set).
// ---------------------------------------------------------------------------

// ------- bucket fill with degree count: esrc[dst*CAP + cnt[dst]++] = src -----
__global__ __launch_bounds__(256) void bucket_kernel(
    const int* __restrict__ src, const int* __restrict__ dst,
    int* __restrict__ cnt, int* __restrict__ esrc, int E) {
  int e = blockIdx.x * 256 + threadIdx.x;
  if (e < E) {
    int d = dst[e];
    int pos = atomicAdd(&cnt[d], 1);
    if (pos < CAP) esrc[d * CAP + pos] = src[e];
  }
}

// ---------------- fused prep: cnt zero + all weight/input reformats ----------
// sections by blockIdx:
//   [0, 5008)        featb2: feat f32 row-major -> blocked bf16 (Kc=64)
//   [5008, 5136)     BW0b:   fc_w f32 [n][k] -> blocked bf16 (Kc=64, 8 nblk)
//   [5136, 5392)     BT1b:   [w1_1; w2_1]^T -> blocked bf16 (Kc=128)
//   [5392, 5648)     BT2b:   [w1_2; w2_2]^T -> blocked bf16 (Kc=128)
//   [5648, 5727)     cnt zero
#define PREP_BLOCKS 5727
__global__ __launch_bounds__(256) void prep_kernel(
    const float* __restrict__ feat, const float* __restrict__ fc_w,
    const float* __restrict__ w1_1, const float* __restrict__ w2_1,
    const float* __restrict__ w1_2, const float* __restrict__ w2_2,
    bf16_t* __restrict__ featb2, bf16_t* __restrict__ bw0,
    bf16_t* __restrict__ bt1, bf16_t* __restrict__ bt2,
    int* __restrict__ cnt) {
  int b = blockIdx.x, t = threadIdx.x;
  if (b < 5008) {
    // c = blk*4096 + r*64 + kc (kc-minor: coalesced 32B f32 reads)
    int c = b * 256 + t;
    int kc = c & 63, r = (c >> 6) & 63, blk = c >> 12;
    int row = blk * 64 + r;
    if (row < NN) {
      const float* s = feat + (size_t)row * 512 + kc * 8;
      float4 v0 = *(const float4*)s, v1 = *(const float4*)(s + 4);
      bf16x8 o = {(bf16_t)v0.x, (bf16_t)v0.y, (bf16_t)v0.z, (bf16_t)v0.w,
                  (bf16_t)v1.x, (bf16_t)v1.y, (bf16_t)v1.z, (bf16_t)v1.w};
      *(bf16x8*)(featb2 + ((size_t)(blk * 64 + kc) * 64 + r) * 8) = o;
    }
  } else if (b < 5136) {
    int c = (b - 5008) * 256 + t;   // 8 blks x 64 r x 64 kc
    int kc = c & 63, r = (c >> 6) & 63, blk = c >> 12;
    const float* s = fc_w + (size_t)(blk * 64 + r) * 512 + kc * 8;
    float4 v0 = *(const float4*)s, v1 = *(const float4*)(s + 4);
    bf16x8 o = {(bf16_t)v0.x, (bf16_t)v0.y, (bf16_t)v0.z, (bf16_t)v0.w,
                (bf16_t)v1.x, (bf16_t)v1.y, (bf16_t)v1.z, (bf16_t)v1.w};
    *(bf16x8*)(bw0 + ((size_t)(blk * 64 + kc) * 64 + r) * 8) = o;
  } else if (b < 5648) {
    // BT: c = (nblk*128 + kc)*64 + nr (n-minor: coalesced reads AND writes)
    int base = (b < 5392) ? 5136 : 5392;
    const float* Wa = (b < 5392) ? w1_1 : w1_2;
    const float* Wb = (b < 5392) ? w2_1 : w2_2;
    bf16_t* bt = (b < 5392) ? bt1 : bt2;
    int c = (b - base) * 256 + t;
    int nr = c & 63, kc = (c >> 6) & 127, nblk = c >> 13;
    const float* W = (kc < 64) ? Wa : Wb;
    int kcw = kc & 63;
    int n = nblk * 64 + nr;
    bf16x8 o;
#pragma unroll
    for (int e = 0; e < 8; ++e)
      o[e] = (bf16_t)W[(size_t)(kcw * 8 + e) * 512 + n];   // W[k][n]
    *(bf16x8*)(bt + (size_t)c * 8) = o;
  } else {
    int i = (b - 5648) * 256 + t;
    if (i < NN) cnt[i] = 0;
  }
}

// ------------- bucket aggregate: one wave per dst node, lane owns 8 dims -----
// f = 0.9 * rsqrt(deg[node]) * sum_e rsqrt(deg[src_e]) * hin[src_e]
// writes the f-half of blocked Acat (kc = lane, 0..63).
// Depth-8 software pipeline with NAMED registers (dynamic-index arrays spill
// to scratch). rsqrt computed inline from cnt.
__global__ __launch_bounds__(256) void aggregate_kernel(
    const bf16_t* __restrict__ hin, const int* __restrict__ cnt,
    const int* __restrict__ esrc, bf16_t* __restrict__ Acat) {
  int node = blockIdx.x * 4 + (threadIdx.x >> 6);
  if (node >= NN) return;
  int lane = threadIdx.x & 63;
  const int* eb = esrc + (size_t)node * CAP;
  int ne_raw = cnt[node];
  int n_e = ne_raw < CAP ? ne_raw : CAP;

  float acc[8] = {};
  bf16x8 v0 = {}, v1 = {}, v2 = {}, v3 = {}, v4 = {}, v5 = {}, v6 = {}, v7 = {};
  float ns0 = 0, ns1 = 0, ns2 = 0, ns3 = 0, ns4 = 0, ns5 = 0, ns6 = 0, ns7 = 0;

#define LOADJ(j, idx)                                                  \
  {                                                                    \
    int s = eb[idx];                                                   \
    ns##j = rsqrtf(fmaxf((float)cnt[s], 1.0f));                        \
    v##j = *(const bf16x8*)(hin + (size_t)s * DD + lane * 8);          \
  }
#define SLOT(j, i)                                                     \
  if ((i) + (j) < n_e) {                                               \
    bf16x8 a = v##j; float na = ns##j;                                 \
    if ((i) + (j) + 8 < n_e) LOADJ(j, (i) + (j) + 8)                   \
    _Pragma("unroll")                                                  \
    for (int k = 0; k < 8; ++k) acc[k] += na * (float)a[k];            \
  }

  if (0 < n_e) LOADJ(0, 0)
  if (1 < n_e) LOADJ(1, 1)
  if (2 < n_e) LOADJ(2, 2)
  if (3 < n_e) LOADJ(3, 3)
  if (4 < n_e) LOADJ(4, 4)
  if (5 < n_e) LOADJ(5, 5)
  if (6 < n_e) LOADJ(6, 6)
  if (7 < n_e) LOADJ(7, 7)

  for (int i = 0; i < n_e; i += 8) {
    SLOT(0, i)
    SLOT(1, i)
    SLOT(2, i)
    SLOT(3, i)
    SLOT(4, i)
    SLOT(5, i)
    SLOT(6, i)
    SLOT(7, i)
  }
#undef SLOT
#undef LOADJ

  float nd = 0.9f * rsqrtf(fmaxf((float)ne_raw, 1.0f));
  bf16x8 ob;
#pragma unroll
  for (int k = 0; k < 8; ++k) ob[k] = (bf16_t)(nd * acc[k]);
  // blocked Acat: chunk = ((node/64)*128 + lane)*64 + node%64   (kc = lane)
  *(bf16x8*)(Acat + (((size_t)(node >> 6) * 128 + lane) * 64 + (node & 63)) * 8) = ob;
}

// -------- GEMM: C = A2(blocked) @ B2(blocked), no LDS, reg ping-pong --------
// Tile 64x128, 4 waves (2x2, 32x64 each), BK=32/iter, unroll-by-2 with named
// ping (p) / pong (q) fragment sets: LOAD(q,kt+1); MFMA(p); LOAD(p,kt+2);
// MFMA(q). Compiler emits vmcnt(6) before each MFMA set -> every load has a
// full MFMA phase (+ other waves) of latency cover. VGPR ~100 -> 4 waves/SIMD.
//   bIdx = (m%8) + 8*(n + 4*(m/8))
// MODE 0: h = acc + bias -> outb bf16 (row-major); blocked acat2 h-half = 0.1h
// MODE 1/2: fs = f + f0 read from blocked acat_ro halves;
//           r = relu((1-beta)*fs + beta*acc + bias) -> MODE1 outb, MODE2 outf
template <int MODE>
__global__ __launch_bounds__(256) void gemm_kernel(
    const bf16_t* __restrict__ A2, const bf16_t* __restrict__ B2,
    int Kc, int M,
    const float* __restrict__ bias,
    const bf16_t* __restrict__ acat_ro, float beta,
    float* __restrict__ outf, bf16_t* __restrict__ outb,
    bf16_t* __restrict__ acat2) {
  const int bid = blockIdx.x;
  const int mt = (bid >> 5) * 8 + (bid & 7);   // m-tile (= m blk64)
  const int nt = (bid >> 3) & 3;               // n-tile
  const int m0 = mt * 64;
  if (m0 >= M) return;
  const int n0 = nt * 128;

  const int t = threadIdx.x;
  const int lane = t & 63;
  const int w = t >> 6;
  const int wm = w & 1, wn = w >> 1;
  const int quad = lane >> 4, m16 = lane & 15;

  // fragment base pointers (blocked layout; quad picks the k-chunk)
  const bf16_t* pa = A2 + (((size_t)mt * Kc + quad) * 64 + wm * 32 + m16) * 8;
  const bf16_t* pb = B2 + (((size_t)(nt * 2 + wn) * Kc + quad) * 64 + m16) * 8;

  floatx4 acc[2][4] = {};
  const int niter = Kc >> 2;   // BK=32 -> 4 chunks/iter; 16 or 32 (even, >=4)

  bf16x8 a0p, a1p, b0p, b1p, b2p, b3p;   // ping
  bf16x8 a0q, a1q, b0q, b1q, b2q, b3q;   // pong

#define LOADSET(s, it)                                                  \
  {                                                                     \
    const bf16_t* xa = pa + (size_t)(it) * 2048;                        \
    const bf16_t* xb = pb + (size_t)(it) * 2048;                        \
    a0##s = *(const bf16x8*)(xa);                                       \
    a1##s = *(const bf16x8*)(xa + 128);                                 \
    b0##s = *(const bf16x8*)(xb);                                       \
    b1##s = *(const bf16x8*)(xb + 128);                                 \
    b2##s = *(const bf16x8*)(xb + 256);                                 \
    b3##s = *(const bf16x8*)(xb + 384);                                 \
  }
#define MFMASET(s)                                                                       \
  acc[0][0] = __builtin_amdgcn_mfma_f32_16x16x32_bf16(a0##s, b0##s, acc[0][0], 0, 0, 0); \
  acc[0][1] = __builtin_amdgcn_mfma_f32_16x16x32_bf16(a0##s, b1##s, acc[0][1], 0, 0, 0); \
  acc[0][2] = __builtin_amdgcn_mfma_f32_16x16x32_bf16(a0##s, b2##s, acc[0][2], 0, 0, 0); \
  acc[0][3] = __builtin_amdgcn_mfma_f32_16x16x32_bf16(a0##s, b3##s, acc[0][3], 0, 0, 0); \
  acc[1][0] = __builtin_amdgcn_mfma_f32_16x16x32_bf16(a1##s, b0##s, acc[1][0], 0, 0, 0); \
  acc[1][1] = __builtin_amdgcn_mfma_f32_16x16x32_bf16(a1##s, b1##s, acc[1][1], 0, 0, 0); \
  acc[1][2] = __builtin_amdgcn_mfma_f32_16x16x32_bf16(a1##s, b2##s, acc[1][2], 0, 0, 0); \
  acc[1][3] = __builtin_amdgcn_mfma_f32_16x16x32_bf16(a1##s, b3##s, acc[1][3], 0, 0, 0);

  LOADSET(p, 0)
  int kt = 0;
  for (; kt + 2 < niter; kt += 2) {
    LOADSET(q, kt + 1)
    MFMASET(p)
    LOADSET(p, kt + 2)
    MFMASET(q)
  }
  // tail pair: kt == niter-2
  LOADSET(q, kt + 1)
  MFMASET(p)
  MFMASET(q)

#undef LOADSET
#undef MFMASET

  // epilogue: C/D layout col = lane&15, row = quad*4 + reg
#pragma unroll
  for (int i = 0; i < 2; ++i) {
#pragma unroll
    for (int j = 0; j < 4; ++j) {
      int col = n0 + wn * 64 + j * 16 + m16;
      float bv = bias[col];
#pragma unroll
      for (int p = 0; p < 4; ++p) {
        int row = m0 + wm * 32 + i * 16 + quad * 4 + p;
        if (row < M) {
          size_t idx = (size_t)row * DD + col;
          float v = acc[i][j][p];
          if constexpr (MODE == 0) {
            float hv = v + bv;
            outb[idx] = (bf16_t)hv;
            // blocked acat2 h-half: kc = 64 + col/8
            acat2[((size_t)(mt * 128 + 64 + (col >> 3)) * 64 + (row & 63)) * 8 +
                  (col & 7)] = (bf16_t)(0.1f * hv);
          } else {
            size_t base = ((size_t)(mt * 128 + (col >> 3)) * 64 + (row & 63)) * 8 +
                          (col & 7);
            float fsv = (float)acat_ro[base] +
                        (float)acat_ro[base + (size_t)64 * 64 * 8];
            float r = (1.0f - beta) * fsv + beta * v + bv;
            r = fmaxf(r, 0.0f);
            if constexpr (MODE == 1) outb[idx] = (bf16_t)r;
            else outf[idx] = r;
          }
        }
      }
    }
  }
}

extern "C" void kernel_launch(void* const* d_in, const int* in_sizes, int n_in,
                              void* d_out, int out_size, void* d_ws, size_t ws_size,
                              hipStream_t stream) {
  const float* feat = (const float*)d_in[0];
  const int* src = (const int*)d_in[1];
  const int* dst = (const int*)d_in[2];
  const float* fc_w = (const float*)d_in[3];
  const float* fc_b = (const float*)d_in[4];
  const float* w1_1 = (const float*)d_in[5];
  const float* w2_1 = (const float*)d_in[6];
  const float* b_1  = (const float*)d_in[7];
  const float* w1_2 = (const float*)d_in[8];
  const float* w2_2 = (const float*)d_in[9];
  const float* b_2  = (const float*)d_in[10];
  float* out = (float*)d_out;

  char* ws = (char*)d_ws;
  size_t off = 0;
  auto alloc = [&](size_t bytes) {
    char* p = ws + off;
    off += (bytes + 255) & ~(size_t)255;
    return p;
  };
  const size_t NDf = (size_t)NN * DD;
  bf16_t* h_bf   = (bf16_t*)alloc(NDf * sizeof(bf16_t));                   // 20.48 MB
  bf16_t* res_bf = (bf16_t*)alloc(NDf * sizeof(bf16_t));                   // 20.48 MB
  bf16_t* featb2 = (bf16_t*)alloc((size_t)NBLK * 64 * 64 * 8 * sizeof(bf16_t));  // 20.5 MB blocked
  bf16_t* Acat2  = (bf16_t*)alloc((size_t)NBLK * 128 * 64 * 8 * sizeof(bf16_t)); // 41 MB blocked
  bf16_t* BW0b   = (bf16_t*)alloc((size_t)8 * 64 * 64 * 8 * sizeof(bf16_t));
  bf16_t* BT1b   = (bf16_t*)alloc((size_t)8 * 128 * 64 * 8 * sizeof(bf16_t));
  bf16_t* BT2b   = (bf16_t*)alloc((size_t)8 * 128 * 64 * 8 * sizeof(bf16_t));
  int*    cnt    = (int*)alloc((size_t)NN * sizeof(int));
  int*    esrc   = (int*)alloc((size_t)NN * CAP * sizeof(int));            // 7.68 MB

  // prep: cnt zero + featb2 + BW0b + BT1b + BT2b (all independent)
  prep_kernel<<<PREP_BLOCKS, 256, 0, stream>>>(feat, fc_w, w1_1, w2_1, w1_2, w2_2,
                                               featb2, BW0b, BT1b, BT2b, cnt);
  // bucket build (counts + slots in one pass)
  bucket_kernel<<<(EE + 255) / 256, 256, 0, stream>>>(src, dst, cnt, esrc, EE);

  const int gblocks = 1280;   // 313 m-tiles (swizzle range 320) x 4 n-tiles

  // h = feat @ fc_w^T + fc_b  (row-major h_bf AND blocked Acat h-half = 0.1*h)
  gemm_kernel<0><<<gblocks, 256, 0, stream>>>(featb2, BW0b, 64, NN, fc_b,
                                              nullptr, 0.0f, nullptr, h_bf, Acat2);

  // ---- layer 1 ----
  aggregate_kernel<<<(NN + 3) / 4, 256, 0, stream>>>(h_bf, cnt, esrc, Acat2);
  gemm_kernel<1><<<gblocks, 256, 0, stream>>>(Acat2, BT1b, 128, NN, b_1,
                                              Acat2, BETA1, nullptr, res_bf, nullptr);

  // ---- layer 2 ----
  aggregate_kernel<<<(NN + 3) / 4, 256, 0, stream>>>(res_bf, cnt, esrc, Acat2);
  gemm_kernel<2><<<gblocks, 256, 0, stream>>>(Acat2, BT2b, 128, NN, b_2,
                                              Acat2, BETA2, out, nullptr, nullptr);
}

// Round 7
// 360.695 us; speedup vs baseline: 1.0959x; 1.0959x over previous
//
#include <hip/hip_runtime.h>
#include <hip/hip_bf16.h>
#include <stdint.h>
#include <stddef.h>

typedef __bf16 bf16_t;
typedef __bf16 bf16x4 __attribute__((ext_vector_type(4)));
typedef __bf16 bf16x8 __attribute__((ext_vector_type(8)));
typedef float floatx4 __attribute__((ext_vector_type(4)));

#define NN 20000
#define EE 320000
#define DD 512
#define CAP 96
#define BETA1 0.6931471805599453f
#define BETA2 0.40546510810816444f

// async global->LDS, 16B per lane. LDS dest must be wave-uniform base + lane*16.
__device__ __forceinline__ void gload16(const bf16_t* g, bf16_t* l) {
  __builtin_amdgcn_global_load_lds((const __attribute__((address_space(1))) uint32_t*)g,
                                   (__attribute__((address_space(3))) uint32_t*)l, 16, 0, 0);
}

// ------- bucket fill with degree count: esrc[dst*CAP + cnt[dst]++] = src -----
__global__ __launch_bounds__(256) void bucket_kernel(
    const int* __restrict__ src, const int* __restrict__ dst,
    int* __restrict__ cnt, int* __restrict__ esrc, int E) {
  int e = blockIdx.x * 256 + threadIdx.x;
  if (e < E) {
    int d = dst[e];
    int pos = atomicAdd(&cnt[d], 1);
    if (pos < CAP) esrc[d * CAP + pos] = src[e];
  }
}

// ---------------- fused prep: cnt zero + all weight/input reformats ----------
// Replaces 5 separate launches (round-2: memset + cvt + cvt + transpose x2).
// sections by blockIdx:
//   [0, 5000)        featb: feat f32 row-major -> bf16 row-major (8 elem/thr)
//   [5000, 5128)     BW0:   fc_w f32 [n][k] -> bf16 row-major (= B^T layout)
//   [5128, 5384)     BT1:   [w1_1; w2_1]^T -> bf16 BT[n][k], k<1024
//   [5384, 5640)     BT2:   [w1_2; w2_2]^T -> bf16
//   [5640, 5719)     cnt zero
#define PREP_BLOCKS 5719
__global__ __launch_bounds__(256) void prep_kernel(
    const float* __restrict__ feat, const float* __restrict__ fc_w,
    const float* __restrict__ w1_1, const float* __restrict__ w2_1,
    const float* __restrict__ w1_2, const float* __restrict__ w2_2,
    bf16_t* __restrict__ featb, bf16_t* __restrict__ bw0,
    bf16_t* __restrict__ bt1, bf16_t* __restrict__ bt2,
    int* __restrict__ cnt) {
  int b = blockIdx.x, t = threadIdx.x;
  if (b < 5128) {
    // straight cvt, 8 f32 -> bf16x8 per thread
    const float* in = (b < 5000) ? feat : fc_w;
    bf16_t* out = (b < 5000) ? featb : bw0;
    size_t c = (size_t)(b < 5000 ? b : b - 5000) * 256 + t;
    const float* s = in + c * 8;
    float4 v0 = *(const float4*)s, v1 = *(const float4*)(s + 4);
    bf16x8 o = {(bf16_t)v0.x, (bf16_t)v0.y, (bf16_t)v0.z, (bf16_t)v0.w,
                (bf16_t)v1.x, (bf16_t)v1.y, (bf16_t)v1.z, (bf16_t)v1.w};
    *(bf16x8*)(out + c * 8) = o;
  } else if (b < 5640) {
    // BT[n][k] = W[k][n], W = [W1; W2] stacked in k. 8 k per thread.
    int base = (b < 5384) ? 5128 : 5384;
    const float* Wa = (b < 5384) ? w1_1 : w1_2;
    const float* Wb = (b < 5384) ? w2_1 : w2_2;
    bf16_t* bt = (b < 5384) ? bt1 : bt2;
    int c = (b - base) * 256 + t;        // [0, 65536)
    int n = c >> 7, kc = c & 127;
    const float* W = (kc < 64) ? Wa : Wb;
    int kcw = kc & 63;
    bf16x8 o;
#pragma unroll
    for (int e = 0; e < 8; ++e)
      o[e] = (bf16_t)W[(size_t)(kcw * 8 + e) * 512 + n];   // column-n gather
    *(bf16x8*)(bt + (size_t)n * 1024 + kc * 8) = o;
  } else {
    int i = (b - 5640) * 256 + t;
    if (i < NN) cnt[i] = 0;
  }
}

// ------------- bucket aggregate: one wave per dst node, lane owns 8 dims -----
// f = 0.9 * nrm[node] * sum_e nrm[src_e] * hin[src_e]
// Acat[node][0:512] = bf16(f)      (second half holds 0.1*h, layer-invariant)
// Depth-8 software pipeline with NAMED registers (dynamic-index arrays spill
// to scratch). Round-2 verified body.
__global__ __launch_bounds__(256) void aggregate_kernel(
    const bf16_t* __restrict__ hin, const float* __restrict__ nrm,
    const int* __restrict__ cnt, const int* __restrict__ esrc,
    bf16_t* __restrict__ Acat) {
  int node = blockIdx.x * 4 + (threadIdx.x >> 6);
  if (node >= NN) return;
  int lane = threadIdx.x & 63;
  const int* eb = esrc + (size_t)node * CAP;
  int n_e = cnt[node];
  n_e = n_e < CAP ? n_e : CAP;

  float acc[8] = {};
  bf16x8 v0 = {}, v1 = {}, v2 = {}, v3 = {}, v4 = {}, v5 = {}, v6 = {}, v7 = {};
  float ns0 = 0, ns1 = 0, ns2 = 0, ns3 = 0, ns4 = 0, ns5 = 0, ns6 = 0, ns7 = 0;

#define LOADJ(j, idx)                                                  \
  {                                                                    \
    int s = eb[idx];                                                   \
    ns##j = nrm[s];                                                    \
    v##j = *(const bf16x8*)(hin + (size_t)s * DD + lane * 8);          \
  }
#define SLOT(j, i)                                                     \
  if ((i) + (j) < n_e) {                                               \
    bf16x8 a = v##j; float na = ns##j;                                 \
    if ((i) + (j) + 8 < n_e) LOADJ(j, (i) + (j) + 8)                   \
    _Pragma("unroll")                                                  \
    for (int k = 0; k < 8; ++k) acc[k] += na * (float)a[k];            \
  }

  if (0 < n_e) LOADJ(0, 0)
  if (1 < n_e) LOADJ(1, 1)
  if (2 < n_e) LOADJ(2, 2)
  if (3 < n_e) LOADJ(3, 3)
  if (4 < n_e) LOADJ(4, 4)
  if (5 < n_e) LOADJ(5, 5)
  if (6 < n_e) LOADJ(6, 6)
  if (7 < n_e) LOADJ(7, 7)

  for (int i = 0; i < n_e; i += 8) {
    SLOT(0, i)
    SLOT(1, i)
    SLOT(2, i)
    SLOT(3, i)
    SLOT(4, i)
    SLOT(5, i)
    SLOT(6, i)
    SLOT(7, i)
  }
#undef SLOT
#undef LOADJ

  float nd = 0.9f * nrm[node];
  bf16x8 ob;
#pragma unroll
  for (int k = 0; k < 8; ++k) ob[k] = (bf16_t)(nd * acc[k]);
  *(bf16x8*)(Acat + (size_t)node * 1024 + lane * 8) = ob;
}

// -------- GEMM: C = A(MxK,bf16) @ B(Kx512), B given transposed BT[n][k] ------
// Round-2 verified structure: tile 64x128, 4 waves (2x2, 32x64 each), BK=64,
// 2-buf LDS via global_load_lds, 1 barrier/iter, 48KB LDS -> 3 blocks/CU.
// Swizzle for 128B rows: stored chunk cc = global chunk gc ^ (row&7).
// XCD swizzle: bIdx = (m%8) + 8*(n + 4*(m/8)).
// MODE 0: h = acc + bias -> outb bf16; acat2[row*1024+512+col] = bf16(0.1*h);
//         ALSO blocks >= 1280 compute nrm[] from cnt[] and exit (piggyback:
//         saves the separate norm launch; runs after bucket, before aggregate).
// MODE 1/2: fs = Acat[row][col] + Acat[row][512+col] (bf16 halves);
//           r = relu((1-beta)*fs + beta*acc + bias) -> MODE1 bf16 outb, MODE2 f32 outf
template <int MODE>
__global__ __launch_bounds__(256) void gemm_kernel(
    const bf16_t* __restrict__ A, const bf16_t* __restrict__ BT,
    int lda, int ldb, int K, int M,
    const float* __restrict__ bias,
    const bf16_t* __restrict__ acat_ro, float beta,
    float* __restrict__ outf, bf16_t* __restrict__ outb,
    bf16_t* __restrict__ acat2,
    const int* __restrict__ cnt, float* __restrict__ nrm) {
  __shared__ bf16_t As[2][64 * 64];    // 8 KB per buf
  __shared__ bf16_t Bs[2][128 * 64];   // 16 KB per buf

  const int bid = blockIdx.x;
  if constexpr (MODE == 0) {
    if (bid >= 1280) {   // norm piggyback blocks
      int i = (bid - 1280) * 256 + threadIdx.x;
      if (i < NN) nrm[i] = 1.0f / sqrtf(fmaxf((float)cnt[i], 1.0f));
      return;
    }
  }
  const int mt = (bid >> 5) * 8 + (bid & 7);   // m-tile
  const int nt = (bid >> 3) & 3;               // n-tile
  const int m0 = mt * 64;
  if (m0 >= M) return;
  const int n0 = nt * 128;

  const int t = threadIdx.x;
  const int lane = t & 63;
  const int w = t >> 6;
  const int wm = w & 1, wn = w >> 1;
  const int quad = lane >> 4, m16 = lane & 15;

  // staging: LDS-linear chunk c_l -> row r=c_l>>3, slot cc=c_l&7 holds global
  // chunk gc = cc ^ (r&7). Thread t stages c_l = t (+256 [+512 +768 for B]).
  const int tr = t >> 3;
  const int gc = (t & 7) ^ (tr & 7);
  int arow0 = m0 + tr;      arow0 = arow0 < M ? arow0 : M - 1;  // clamp OOB
  int arow1 = m0 + tr + 32; arow1 = arow1 < M ? arow1 : M - 1;
  const bf16_t* agp0 = A + (size_t)arow0 * lda + gc * 8;
  const bf16_t* agp1 = A + (size_t)arow1 * lda + gc * 8;
  const bf16_t* bgp0 = BT + (size_t)(n0 + tr) * ldb + gc * 8;
  const bf16_t* bgp1 = BT + (size_t)(n0 + tr + 32) * ldb + gc * 8;
  const bf16_t* bgp2 = BT + (size_t)(n0 + tr + 64) * ldb + gc * 8;
  const bf16_t* bgp3 = BT + (size_t)(n0 + tr + 96) * ldb + gc * 8;

#define STAGE(buf, ko)                              \
  gload16(agp0 + (ko), &As[buf][t * 8]);            \
  gload16(agp1 + (ko), &As[buf][(t + 256) * 8]);    \
  gload16(bgp0 + (ko), &Bs[buf][t * 8]);            \
  gload16(bgp1 + (ko), &Bs[buf][(t + 256) * 8]);    \
  gload16(bgp2 + (ko), &Bs[buf][(t + 512) * 8]);    \
  gload16(bgp3 + (ko), &Bs[buf][(t + 768) * 8]);

  floatx4 acc[2][4] = {};
  const int niter = K >> 6;

  // stage buffer 0
  STAGE(0, 0)

  for (int kt = 0; kt < niter; ++kt) {
    __syncthreads();   // drains buf kt's loads (issued one iter ago)
    const int b = kt & 1;
    if (kt + 1 < niter) {        // prefetch next buffer during compute
      const int ko = (kt + 1) * 64;
      STAGE(b ^ 1, ko)
    }

#pragma unroll
    for (int ks = 0; ks < 2; ++ks) {
      bf16x8 af[2], bfr[4];
#pragma unroll
      for (int i = 0; i < 2; ++i) {
        int arow = wm * 32 + i * 16 + m16;
        int cc = (ks * 4 + quad) ^ (arow & 7);
        af[i] = *(const bf16x8*)(&As[b][(arow * 8 + cc) * 8]);
      }
#pragma unroll
      for (int j = 0; j < 4; ++j) {
        int brow = wn * 64 + j * 16 + m16;
        int cc = (ks * 4 + quad) ^ (brow & 7);
        bfr[j] = *(const bf16x8*)(&Bs[b][(brow * 8 + cc) * 8]);
      }
#pragma unroll
      for (int i = 0; i < 2; ++i)
#pragma unroll
        for (int j = 0; j < 4; ++j)
          acc[i][j] = __builtin_amdgcn_mfma_f32_16x16x32_bf16(af[i], bfr[j], acc[i][j], 0, 0, 0);
    }
  }
#undef STAGE

  // epilogue: C/D layout col = lane&15, row = quad*4 + reg
#pragma unroll
  for (int i = 0; i < 2; ++i) {
#pragma unroll
    for (int j = 0; j < 4; ++j) {
      int col = n0 + wn * 64 + j * 16 + m16;
      float bv = bias[col];
#pragma unroll
      for (int p = 0; p < 4; ++p) {
        int row = m0 + wm * 32 + i * 16 + quad * 4 + p;
        if (row < M) {
          size_t idx = (size_t)row * DD + col;
          float v = acc[i][j][p];
          if constexpr (MODE == 0) {
            float hv = v + bv;
            outb[idx] = (bf16_t)hv;
            acat2[(size_t)row * 1024 + 512 + col] = (bf16_t)(0.1f * hv);
          } else {
            float fsv = (float)acat_ro[(size_t)row * 1024 + col] +
                        (float)acat_ro[(size_t)row * 1024 + 512 + col];
            float r = (1.0f - beta) * fsv + beta * v + bv;
            r = fmaxf(r, 0.0f);
            if constexpr (MODE == 1) outb[idx] = (bf16_t)r;
            else outf[idx] = r;
          }
        }
      }
    }
  }
}

extern "C" void kernel_launch(void* const* d_in, const int* in_sizes, int n_in,
                              void* d_out, int out_size, void* d_ws, size_t ws_size,
                              hipStream_t stream) {
  const float* feat = (const float*)d_in[0];
  const int* src = (const int*)d_in[1];
  const int* dst = (const int*)d_in[2];
  const float* fc_w = (const float*)d_in[3];
  const float* fc_b = (const float*)d_in[4];
  const float* w1_1 = (const float*)d_in[5];
  const float* w2_1 = (const float*)d_in[6];
  const float* b_1  = (const float*)d_in[7];
  const float* w1_2 = (const float*)d_in[8];
  const float* w2_2 = (const float*)d_in[9];
  const float* b_2  = (const float*)d_in[10];
  float* out = (float*)d_out;

  char* ws = (char*)d_ws;
  size_t off = 0;
  auto alloc = [&](size_t bytes) {
    char* p = ws + off;
    off += (bytes + 255) & ~(size_t)255;
    return p;
  };
  const size_t NDf = (size_t)NN * DD;               // 10.24M elements
  bf16_t* h_bf   = (bf16_t*)alloc(NDf * sizeof(bf16_t));        // 20.48 MB
  bf16_t* res_bf = (bf16_t*)alloc(NDf * sizeof(bf16_t));        // 20.48 MB
  bf16_t* featb  = (bf16_t*)alloc(NDf * sizeof(bf16_t));        // 20.48 MB
  bf16_t* Acat   = (bf16_t*)alloc((size_t)NN * 1024 * sizeof(bf16_t));  // 40.96 MB
  bf16_t* BW0    = (bf16_t*)alloc((size_t)512 * 512 * sizeof(bf16_t));
  bf16_t* BT1    = (bf16_t*)alloc((size_t)512 * 1024 * sizeof(bf16_t));
  bf16_t* BT2    = (bf16_t*)alloc((size_t)512 * 1024 * sizeof(bf16_t));
  int*    cnt    = (int*)alloc((size_t)NN * sizeof(int));
  float*  nrm    = (float*)alloc((size_t)NN * sizeof(float));
  int*    esrc   = (int*)alloc((size_t)NN * CAP * sizeof(int)); // 7.68 MB

  // 1. fused prep: featb/BW0/BT1/BT2 reformats + cnt zero
  prep_kernel<<<PREP_BLOCKS, 256, 0, stream>>>(feat, fc_w, w1_1, w2_1, w1_2, w2_2,
                                               featb, BW0, BT1, BT2, cnt);
  // 2. bucket build (counts + slots in one pass)
  bucket_kernel<<<(EE + 255) / 256, 256, 0, stream>>>(src, dst, cnt, esrc, EE);

  // 313 m-tiles of 64 rows, 4 n-tiles; swizzled grid covers m<320 -> 1280 blocks
  // 3. h = feat @ fc_w^T + fc_b (h_bf + Acat f0-half); +79 norm piggyback blocks
  gemm_kernel<0><<<1280 + 79, 256, 0, stream>>>(featb, BW0, 512, 512, 512, NN, fc_b,
                                                nullptr, 0.0f, nullptr, h_bf, Acat,
                                                cnt, nrm);

  // ---- layer 1 ----
  aggregate_kernel<<<(NN + 3) / 4, 256, 0, stream>>>(h_bf, nrm, cnt, esrc, Acat);
  gemm_kernel<1><<<1280, 256, 0, stream>>>(Acat, BT1, 1024, 1024, 1024, NN, b_1,
                                           Acat, BETA1, nullptr, res_bf, nullptr,
                                           nullptr, nullptr);

  // ---- layer 2 ----
  aggregate_kernel<<<(NN + 3) / 4, 256, 0, stream>>>(res_bf, nrm, cnt, esrc, Acat);
  gemm_kernel<2><<<1280, 256, 0, stream>>>(Acat, BT2, 1024, 1024, 1024, NN, b_2,
                                           Acat, BETA2, out, nullptr, nullptr,
                                           nullptr, nullptr);
}